// Round 20
// baseline (77.278 us; speedup 1.0000x reference)
//
#include <hip/hip_runtime.h>

#define NCAP 10     // capsule classes c
#define NB   256    // batch b
#define NN   1152   // route nodes n
#define KI   8      // input dim i
#define NO   16     // output dim o
#define NT   1024   // threads per block (16 waves)
#define NWV  16
#define TB   4      // batches per block (W read once, used 4x)
#define NITER 3

typedef float v2f __attribute__((ext_vector_type(2)));

// Round-13 structure at TB=4: W traffic halves (the largest pipe). 144 KB
// bf16 priors -> 1 block/CU; compensations: all-wave redundant finalize (a
// lone block can't hide a wave-0-only finalize) and pk-f32 routing (fits the
// 128-reg cap of 1024-thread blocks; round 15's spill was the 64-reg clamp).
__global__ __launch_bounds__(NT) void capsule_kernel(
    const float* __restrict__ x,    // [256,1152,8]
    const float* __restrict__ w,    // [10,1152,8,16]
    float* __restrict__ out)        // [10,256,16]
{
    __shared__ unsigned s_pr[TB * NN * 8];    // 144 KB bf16-pair priors
    __shared__ float s_red2[NWV][TB][NO];     // per-wave comp partials (4 KB)
    __shared__ float s_ls[NWV][TB];           // per-wave exp-sum partials
    __shared__ float s_v[TB][NO];             // squashed v broadcast

    const int t    = threadIdx.x;
    const int wv   = t >> 6;
    const int lane = t & 63;
    const int j    = t & 3;        // build: o-quad owned by this lane
    const int g    = t >> 2;       // build: cluster id, 0..255

    // XCD swizzle: 640 % 8 == 0 -> bijective; same-c blocks share an XCD L2.
    const int bid = blockIdx.x;
    const int swz = (bid & 7) * (NCAP * (NB / TB) / 8) + (bid >> 3);
    const int c   = swz >> 6;              // / (NB/TB) = /64
    const int b0  = (swz & 63) * TB;

    const int bl0 = lane & 1, bl1 = (lane >> 1) & 1,
              bl2 = (lane >> 2) & 1, bl3 = (lane >> 3) & 1;

    // 16B-slot index within a tb-plane (quad q of row n)
    auto slotof = [](int n, int q) { return 2 * n + (q ^ ((n >> 2) & 1)); };

    // iter-1 weighted sum (softmax(0) uniform) accumulated in f32 during build
    float bs[TB][4];
    #pragma unroll
    for (int tb = 0; tb < TB; ++tb)
        bs[tb][0] = bs[tb][1] = bs[tb][2] = bs[tb][3] = 0.f;

    // ---- build: 4-lane cluster per n; lane j computes o-quad j ----
    auto build_round = [&](int n) {
        const float4* wp = reinterpret_cast<const float4*>(
            w + ((size_t)c * NN + n) * (KI * NO));
        float xs[TB][KI];
        #pragma unroll
        for (int tb = 0; tb < TB; ++tb) {
            const float4* xp = reinterpret_cast<const float4*>(
                x + ((size_t)(b0 + tb) * NN + n) * KI);
            float4 a = xp[0], b = xp[1];   // same addr across cluster -> bcast
            xs[tb][0]=a.x; xs[tb][1]=a.y; xs[tb][2]=a.z; xs[tb][3]=a.w;
            xs[tb][4]=b.x; xs[tb][5]=b.y; xs[tb][6]=b.z; xs[tb][7]=b.w;
        }
        float acc[TB][4];
        #pragma unroll
        for (int tb = 0; tb < TB; ++tb)
            acc[tb][0] = acc[tb][1] = acc[tb][2] = acc[tb][3] = 0.f;
        #pragma unroll
        for (int i = 0; i < KI; ++i) {
            float4 wq = wp[i * 4 + j];     // dense 64B lines across wave
            #pragma unroll
            for (int tb = 0; tb < TB; ++tb) {
                acc[tb][0] = fmaf(xs[tb][i], wq.x, acc[tb][0]);
                acc[tb][1] = fmaf(xs[tb][i], wq.y, acc[tb][1]);
                acc[tb][2] = fmaf(xs[tb][i], wq.z, acc[tb][2]);
                acc[tb][3] = fmaf(xs[tb][i], wq.w, acc[tb][3]);
            }
        }
        const int q = j >> 1, h = j & 1;
        #pragma unroll
        for (int tb = 0; tb < TB; ++tb) {
            bs[tb][0] += acc[tb][0]; bs[tb][1] += acc[tb][1];
            bs[tb][2] += acc[tb][2]; bs[tb][3] += acc[tb][3];
            unsigned p0, p1;   // pair: even op lo16, odd op hi16 (RNE)
            asm("v_cvt_pk_bf16_f32 %0, %1, %2"
                : "=v"(p0) : "v"(acc[tb][0]), "v"(acc[tb][1]));
            asm("v_cvt_pk_bf16_f32 %0, %1, %2"
                : "=v"(p1) : "v"(acc[tb][2]), "v"(acc[tb][3]));
            uint2 pk; pk.x = p0; pk.y = p1;
            *reinterpret_cast<uint2*>(
                &s_pr[tb * (NN * 8) + slotof(n, q) * 4 + h * 2]) = pk;
        }
    };
    #pragma unroll 1
    for (int r = 0; r < 4; ++r) build_round(r * 256 + g);
    if (g < 128) build_round(1024 + g);      // wave-uniform (t < 512)

    // reduce bs across the wave's 16 clusters (same j): lanes 0..3 write
    #pragma unroll
    for (int tb = 0; tb < TB; ++tb)
        #pragma unroll
        for (int k = 0; k < 4; ++k) {
            float s = bs[tb][k];
            s += __shfl_xor(s, 4);  s += __shfl_xor(s, 8);
            s += __shfl_xor(s, 16); s += __shfl_xor(s, 32);
            bs[tb][k] = s;
        }
    if (lane < 4) {
        #pragma unroll
        for (int tb = 0; tb < TB; ++tb) {
            s_red2[wv][tb][4*lane+0] = bs[tb][0];
            s_red2[wv][tb][4*lane+1] = bs[tb][1];
            s_red2[wv][tb][4*lane+2] = bs[tb][2];
            s_red2[wv][tb][4*lane+3] = bs[tb][3];
        }
    }
    __syncthreads();

    // ---- finalize: EVERY wave redundantly combines + squashes; 64 lanes
    // cover tb2 = lane>>4 (0..3) x oc = lane&15; wave 0 publishes ----
    auto finalize = [&](int iter) {
        const int tb2 = lane >> 4, oc = lane & 15;
        float acc = 0.f, lt = 0.f;
        #pragma unroll
        for (int w2 = 0; w2 < NWV; ++w2) {
            acc += s_red2[w2][tb2][oc];      // same addr in 16-grp -> bcast
            if (iter > 0) lt += s_ls[w2][tb2];
        }
        if (iter == 0) lt = (float)NN;       // softmax(0) is uniform
        float s_o = acc / lt;
        float sq = s_o * s_o;
        sq += __shfl_xor(sq, 1); sq += __shfl_xor(sq, 2);
        sq += __shfl_xor(sq, 4); sq += __shfl_xor(sq, 8);
        float scale = sq / ((1.f + sq) * sqrtf(sq));
        float vo = s_o * scale;
        if (wv == 0) {
            s_v[tb2][oc] = vo;
            if (iter == NITER - 1)
                out[((size_t)c * NB + b0 + tb2) * NO + oc] = vo;
        }
    };

    // consumption: thread owns n=t (and 1024+t if t<128) -> private logits;
    // delta + exp + weighted-sum fused in ONE pk-f32 pass over bf16 priors.
    float logit[2][TB];
    #pragma unroll
    for (int tb = 0; tb < TB; ++tb) { logit[0][tb] = 0.f; logit[1][tb] = 0.f; }

    auto routing_pass = [&]() {
        #pragma unroll
        for (int tb = 0; tb < TB; ++tb) {
            v2f vv2[8];
            {
                const float4* vp = reinterpret_cast<const float4*>(&s_v[tb][0]);
                float4 a = vp[0], b = vp[1], cc = vp[2], d4 = vp[3];
                vv2[0] = v2f{a.x,  a.y};  vv2[1] = v2f{a.z,  a.w};
                vv2[2] = v2f{b.x,  b.y};  vv2[3] = v2f{b.z,  b.w};
                vv2[4] = v2f{cc.x, cc.y}; vv2[5] = v2f{cc.z, cc.w};
                vv2[6] = v2f{d4.x, d4.y}; vv2[7] = v2f{d4.z, d4.w};
            }
            v2f sp2[8];
            #pragma unroll
            for (int p = 0; p < 8; ++p) sp2[p] = v2f{0.f, 0.f};
            float lse = 0.f;
            #pragma unroll
            for (int rr = 0; rr < 2; ++rr) {
                if (rr == 1 && t >= 128) continue;   // wave-uniform
                const int n = rr * 1024 + t;
                const unsigned* base = &s_pr[tb * (NN * 8)];
                uint4 qa = *reinterpret_cast<const uint4*>(&base[slotof(n, 0) * 4]);
                uint4 qb = *reinterpret_cast<const uint4*>(&base[slotof(n, 1) * 4]);
                unsigned u[8] = {qa.x, qa.y, qa.z, qa.w, qb.x, qb.y, qb.z, qb.w};
                v2f r2[8];                 // unpack ONCE, reuse in both chains
                #pragma unroll
                for (int op = 0; op < 8; ++op) {
                    r2[op].x = __uint_as_float(u[op] << 16);
                    r2[op].y = __uint_as_float(u[op] & 0xffff0000u);
                }
                v2f d2 = v2f{0.f, 0.f};
                #pragma unroll
                for (int op = 0; op < 8; ++op)
                    d2 = __builtin_elementwise_fma(r2[op], vv2[op], d2);
                logit[rr][tb] += d2.x + d2.y;   // |logit| <~ 30: f32-safe
                float e = __expf(logit[rr][tb]);
                lse += e;
                v2f e2 = v2f{e, e};
                #pragma unroll
                for (int op = 0; op < 8; ++op)
                    sp2[op] = __builtin_elementwise_fma(e2, r2[op], sp2[op]);
            }
            // exp-sum: full-wave butterfly
            float s = lse;
            s += __shfl_xor(s, 1);  s += __shfl_xor(s, 2);
            s += __shfl_xor(s, 4);  s += __shfl_xor(s, 8);
            s += __shfl_xor(s, 16); s += __shfl_xor(s, 32);
            if (lane == 0) s_ls[wv][tb] = s;
            // comp-halving fold: stage 1 consumes sp2 halves directly
            float g8[8];
            #pragma unroll
            for (int r = 0; r < 8; ++r) {
                float keep = bl0 ? sp2[r].y : sp2[r].x;
                float send = bl0 ? sp2[r].x : sp2[r].y;
                g8[r] = keep + __shfl_xor(send, 1);
            }
            float g4[4];
            #pragma unroll
            for (int r = 0; r < 4; ++r) {
                float keep = bl1 ? g8[2*r+1] : g8[2*r];
                float send = bl1 ? g8[2*r]   : g8[2*r+1];
                g4[r] = keep + __shfl_xor(send, 2);
            }
            float g2[2];
            #pragma unroll
            for (int r = 0; r < 2; ++r) {
                float keep = bl2 ? g4[2*r+1] : g4[2*r];
                float send = bl2 ? g4[2*r]   : g4[2*r+1];
                g2[r] = keep + __shfl_xor(send, 4);
            }
            float g1;
            {
                float keep = bl3 ? g2[1] : g2[0];
                float send = bl3 ? g2[0] : g2[1];
                g1 = keep + __shfl_xor(send, 8);
            }
            g1 += __shfl_xor(g1, 16);
            g1 += __shfl_xor(g1, 32);
            if (lane < NO) s_red2[wv][tb][lane] = g1;
        }
    };

    finalize(0);          // v1 from uniform probs (build-side f32 sums)
    __syncthreads();
    routing_pass();       // logits += prior.v1; sums for iter 2
    __syncthreads();
    finalize(1);          // v2
    __syncthreads();
    routing_pass();       // logits += prior.v2; sums for iter 3
    __syncthreads();
    finalize(2);          // v3 -> out
}

extern "C" void kernel_launch(void* const* d_in, const int* in_sizes, int n_in,
                              void* d_out, int out_size, void* d_ws, size_t ws_size,
                              hipStream_t stream) {
    const float* x = (const float*)d_in[0];
    const float* w = (const float*)d_in[1];
    float* out = (float*)d_out;
    capsule_kernel<<<dim3(NCAP * (NB / TB)), dim3(NT), 0, stream>>>(x, w, out);
}

// Round 21
// 61.407 us; speedup vs baseline: 1.2584x; 1.2584x over previous
//
#include <hip/hip_runtime.h>

#define NCAP 10     // capsule classes c
#define NB   256    // batch b
#define NN   1152   // route nodes n
#define KI   8      // input dim i
#define NO   16     // output dim o
#define NT   1024   // threads per block (16 waves)
#define NWV  16
#define TB   2      // batches per block
#define NITER 3

// Round-13 champion (58.5 us) + ONE change: all-wave redundant finalize
// (rounds 9/10 proved the form correct). Removes the 3x per-block stall
// where 32 resident waves waited on a single wave's combine+squash.
// Wave 0 still publishes s_v and the final output.
__global__ __launch_bounds__(NT, 8) void capsule_kernel(
    const float* __restrict__ x,    // [256,1152,8]
    const float* __restrict__ w,    // [10,1152,8,16]
    float* __restrict__ out)        // [10,256,16]
{
    __shared__ unsigned s_pr[TB * NN * 8];    // 72 KB bf16-pair priors
    __shared__ float s_red2[NWV][TB][NO];     // per-wave comp partials
    __shared__ float s_ls[NWV][TB];           // per-wave exp-sum partials
    __shared__ float s_v[TB][NO];             // squashed v broadcast

    const int t    = threadIdx.x;
    const int wv   = t >> 6;
    const int lane = t & 63;
    const int j    = t & 3;        // build: o-quad owned by this lane
    const int g    = t >> 2;       // build: cluster id, 0..255

    // XCD swizzle: 1280 % 8 == 0 -> bijective; same-c blocks share an XCD L2.
    const int bid = blockIdx.x;
    const int swz = (bid & 7) * (NCAP * (NB / TB) / 8) + (bid >> 3);
    const int c   = swz / (NB / TB);
    const int b0  = (swz % (NB / TB)) * TB;

    const int bl0 = lane & 1, bl1 = (lane >> 1) & 1,
              bl2 = (lane >> 2) & 1, bl3 = (lane >> 3) & 1;

    // 16B-slot index within a tb-plane (quad q of row n)
    auto slotof = [](int n, int q) { return 2 * n + (q ^ ((n >> 2) & 1)); };

    // iter-1 weighted sum (softmax(0) uniform) accumulated in f32 during build
    float bs[TB][4] = {{0.f,0.f,0.f,0.f},{0.f,0.f,0.f,0.f}};

    // ---- build: 4-lane cluster per n; lane j computes o-quad j ----
    auto build_round = [&](int n) {
        const float4* wp = reinterpret_cast<const float4*>(
            w + ((size_t)c * NN + n) * (KI * NO));
        float xs[TB][KI];
        #pragma unroll
        for (int tb = 0; tb < TB; ++tb) {
            const float4* xp = reinterpret_cast<const float4*>(
                x + ((size_t)(b0 + tb) * NN + n) * KI);
            float4 a = xp[0], b = xp[1];   // same addr across cluster -> bcast
            xs[tb][0]=a.x; xs[tb][1]=a.y; xs[tb][2]=a.z; xs[tb][3]=a.w;
            xs[tb][4]=b.x; xs[tb][5]=b.y; xs[tb][6]=b.z; xs[tb][7]=b.w;
        }
        float acc[TB][4] = {{0.f,0.f,0.f,0.f},{0.f,0.f,0.f,0.f}};
        #pragma unroll
        for (int i = 0; i < KI; ++i) {
            float4 wq = wp[i * 4 + j];
            #pragma unroll
            for (int tb = 0; tb < TB; ++tb) {
                acc[tb][0] = fmaf(xs[tb][i], wq.x, acc[tb][0]);
                acc[tb][1] = fmaf(xs[tb][i], wq.y, acc[tb][1]);
                acc[tb][2] = fmaf(xs[tb][i], wq.z, acc[tb][2]);
                acc[tb][3] = fmaf(xs[tb][i], wq.w, acc[tb][3]);
            }
        }
        // lane j holds ops {4j..4j+3} = pairs {2j, 2j+1} = 8B in quad j>>1
        const int q = j >> 1, h = j & 1;
        #pragma unroll
        for (int tb = 0; tb < TB; ++tb) {
            bs[tb][0] += acc[tb][0]; bs[tb][1] += acc[tb][1];
            bs[tb][2] += acc[tb][2]; bs[tb][3] += acc[tb][3];
            unsigned p0, p1;   // pair: even op lo16, odd op hi16 (RNE)
            asm("v_cvt_pk_bf16_f32 %0, %1, %2"
                : "=v"(p0) : "v"(acc[tb][0]), "v"(acc[tb][1]));
            asm("v_cvt_pk_bf16_f32 %0, %1, %2"
                : "=v"(p1) : "v"(acc[tb][2]), "v"(acc[tb][3]));
            uint2 pk; pk.x = p0; pk.y = p1;
            *reinterpret_cast<uint2*>(
                &s_pr[tb * (NN * 8) + slotof(n, q) * 4 + h * 2]) = pk;
        }
    };
    #pragma unroll 1
    for (int r = 0; r < 4; ++r) build_round(r * 256 + g);
    if (g < 128) build_round(1024 + g);      // wave-uniform (t < 512)

    // reduce bs across the wave's 16 clusters (same j): lanes 0..3 write
    #pragma unroll
    for (int tb = 0; tb < TB; ++tb)
        #pragma unroll
        for (int k = 0; k < 4; ++k) {
            float s = bs[tb][k];
            s += __shfl_xor(s, 4);  s += __shfl_xor(s, 8);
            s += __shfl_xor(s, 16); s += __shfl_xor(s, 32);
            bs[tb][k] = s;
        }
    if (lane < 4) {
        #pragma unroll
        for (int tb = 0; tb < TB; ++tb) {
            s_red2[wv][tb][4*lane+0] = bs[tb][0];
            s_red2[wv][tb][4*lane+1] = bs[tb][1];
            s_red2[wv][tb][4*lane+2] = bs[tb][2];
            s_red2[wv][tb][4*lane+3] = bs[tb][3];
        }
    }
    __syncthreads();

    // ---- finalize: EVERY wave redundantly combines + squashes (no single-
    // wave stall); lanes 0-15: tb0, 16-31: tb1, 32-63 duplicate. Wave 0
    // publishes s_v (and the output at the last iteration). ----
    auto finalize = [&](int iter) {
        const int tb2 = (lane >> 4) & 1;
        const int oc  = lane & 15;
        float acc = 0.f, lt = 0.f;
        #pragma unroll
        for (int w2 = 0; w2 < NWV; ++w2) {
            acc += s_red2[w2][tb2][oc];      // consecutive/broadcast reads
            if (iter > 0) lt += s_ls[w2][tb2];
        }
        if (iter == 0) lt = (float)NN;       // softmax(0) is uniform
        float s_o = acc / lt;
        float sq = s_o * s_o;
        sq += __shfl_xor(sq, 1); sq += __shfl_xor(sq, 2);
        sq += __shfl_xor(sq, 4); sq += __shfl_xor(sq, 8);
        float scale = sq / ((1.f + sq) * sqrtf(sq));
        float vo = s_o * scale;
        if (wv == 0 && lane < 32) {
            s_v[tb2][oc] = vo;
            if (iter == NITER - 1)
                out[((size_t)c * NB + b0 + tb2) * NO + oc] = vo;
        }
    };

    // consumption: thread owns n=t (and 1024+t if t<128) -> private logits;
    // delta + exp + weighted-sum fused in ONE pass over the bf16 priors.
    float logit[2][TB] = {{0.f,0.f},{0.f,0.f}};

    auto routing_pass = [&]() {
        #pragma unroll
        for (int tb = 0; tb < TB; ++tb) {
            float vv[NO];
            {
                const float4* vp = reinterpret_cast<const float4*>(&s_v[tb][0]);
                float4 a = vp[0], b = vp[1], cc = vp[2], d4 = vp[3];
                vv[0]=a.x;  vv[1]=a.y;  vv[2]=a.z;  vv[3]=a.w;
                vv[4]=b.x;  vv[5]=b.y;  vv[6]=b.z;  vv[7]=b.w;
                vv[8]=cc.x; vv[9]=cc.y; vv[10]=cc.z; vv[11]=cc.w;
                vv[12]=d4.x; vv[13]=d4.y; vv[14]=d4.z; vv[15]=d4.w;
            }
            float sp[NO];
            #pragma unroll
            for (int o = 0; o < NO; ++o) sp[o] = 0.f;
            float lse = 0.f;
            #pragma unroll
            for (int rr = 0; rr < 2; ++rr) {
                if (rr == 1 && t >= 128) continue;   // wave-uniform
                const int n = rr * 1024 + t;
                const unsigned* base = &s_pr[tb * (NN * 8)];
                uint4 qa = *reinterpret_cast<const uint4*>(&base[slotof(n, 0) * 4]);
                uint4 qb = *reinterpret_cast<const uint4*>(&base[slotof(n, 1) * 4]);
                unsigned u[8] = {qa.x, qa.y, qa.z, qa.w, qb.x, qb.y, qb.z, qb.w};
                float d = 0.f;
                #pragma unroll
                for (int op = 0; op < 8; ++op) {
                    float lo = __uint_as_float(u[op] << 16);
                    float hi = __uint_as_float(u[op] & 0xffff0000u);
                    d = fmaf(lo, vv[2*op+0], d);
                    d = fmaf(hi, vv[2*op+1], d);
                }
                logit[rr][tb] += d;        // |logit| <~ 30: fp32 exact-safe
                float e = __expf(logit[rr][tb]);
                lse += e;
                #pragma unroll
                for (int op = 0; op < 8; ++op) {
                    float lo = __uint_as_float(u[op] << 16);
                    float hi = __uint_as_float(u[op] & 0xffff0000u);
                    sp[2*op+0] = fmaf(e, lo, sp[2*op+0]);
                    sp[2*op+1] = fmaf(e, hi, sp[2*op+1]);
                }
            }
            // exp-sum: full-wave butterfly
            float s = lse;
            s += __shfl_xor(s, 1);  s += __shfl_xor(s, 2);
            s += __shfl_xor(s, 4);  s += __shfl_xor(s, 8);
            s += __shfl_xor(s, 16); s += __shfl_xor(s, 32);
            if (lane == 0) s_ls[wv][tb] = s;
            // comp-halving fold: 16 comps over 16-lane groups in 15 shuffles
            float g8[8];
            #pragma unroll
            for (int r = 0; r < 8; ++r) {
                float keep = bl0 ? sp[2*r+1] : sp[2*r];
                float send = bl0 ? sp[2*r]   : sp[2*r+1];
                g8[r] = keep + __shfl_xor(send, 1);
            }
            float g4[4];
            #pragma unroll
            for (int r = 0; r < 4; ++r) {
                float keep = bl1 ? g8[2*r+1] : g8[2*r];
                float send = bl1 ? g8[2*r]   : g8[2*r+1];
                g4[r] = keep + __shfl_xor(send, 2);
            }
            float g2[2];
            #pragma unroll
            for (int r = 0; r < 2; ++r) {
                float keep = bl2 ? g4[2*r+1] : g4[2*r];
                float send = bl2 ? g4[2*r]   : g4[2*r+1];
                g2[r] = keep + __shfl_xor(send, 4);
            }
            float g1;
            {
                float keep = bl3 ? g2[1] : g2[0];
                float send = bl3 ? g2[0] : g2[1];
                g1 = keep + __shfl_xor(send, 8);
            }
            g1 += __shfl_xor(g1, 16);
            g1 += __shfl_xor(g1, 32);
            if (lane < NO) s_red2[wv][tb][lane] = g1;
        }
    };

    finalize(0);          // v1 from uniform probs (build-side f32 sums)
    __syncthreads();
    routing_pass();       // logits += prior.v1; sums for iter 2
    __syncthreads();
    finalize(1);          // v2
    __syncthreads();
    routing_pass();       // logits += prior.v2; sums for iter 3
    __syncthreads();
    finalize(2);          // v3 -> out
}

extern "C" void kernel_launch(void* const* d_in, const int* in_sizes, int n_in,
                              void* d_out, int out_size, void* d_ws, size_t ws_size,
                              hipStream_t stream) {
    const float* x = (const float*)d_in[0];
    const float* w = (const float*)d_in[1];
    float* out = (float*)d_out;
    capsule_kernel<<<dim3(NCAP * (NB / TB)), dim3(NT), 0, stream>>>(x, w, out);
}

// Round 22
// 58.430 us; speedup vs baseline: 1.3226x; 1.0510x over previous
//
#include <hip/hip_runtime.h>

#define NCAP 10     // capsule classes c
#define NB   256    // batch b
#define NN   1152   // route nodes n
#define KI   8      // input dim i
#define NO   16     // output dim o
#define NT   1024   // threads per block (16 waves)
#define NWV  16
#define TB   2      // batches per block
#define NITER 3

// CHAMPION (round 13, 58.5 us): TB=2, 2 blocks/CU (launch_bounds(NT,8) pins
// regs <= 64 -> VGPR 32, zero spill), bf16-pair priors in LDS with
// op-contiguous [tb][n][8 u32] layout + quad swizzle (b128 reads), fused
// delta+exp+weighted-sum routing with thread-private logits.
// All 9 explored perturbations regressed; this is the converged optimum.
__global__ __launch_bounds__(NT, 8) void capsule_kernel(
    const float* __restrict__ x,    // [256,1152,8]
    const float* __restrict__ w,    // [10,1152,8,16]
    float* __restrict__ out)        // [10,256,16]
{
    __shared__ unsigned s_pr[TB * NN * 8];    // 72 KB bf16-pair priors
    __shared__ float s_red2[NWV][TB][NO];     // per-wave comp partials
    __shared__ float s_ls[NWV][TB];           // per-wave exp-sum partials
    __shared__ float s_v[TB][NO];             // squashed v broadcast

    const int t    = threadIdx.x;
    const int wv   = t >> 6;
    const int lane = t & 63;
    const int j    = t & 3;        // build: o-quad owned by this lane
    const int g    = t >> 2;       // build: cluster id, 0..255

    // XCD swizzle: 1280 % 8 == 0 -> bijective; same-c blocks share an XCD L2.
    const int bid = blockIdx.x;
    const int swz = (bid & 7) * (NCAP * (NB / TB) / 8) + (bid >> 3);
    const int c   = swz / (NB / TB);
    const int b0  = (swz % (NB / TB)) * TB;

    const int bl0 = lane & 1, bl1 = (lane >> 1) & 1,
              bl2 = (lane >> 2) & 1, bl3 = (lane >> 3) & 1;

    // 16B-slot index within a tb-plane (quad q of row n)
    auto slotof = [](int n, int q) { return 2 * n + (q ^ ((n >> 2) & 1)); };

    // iter-1 weighted sum (softmax(0) uniform) accumulated in f32 during build
    float bs[TB][4] = {{0.f,0.f,0.f,0.f},{0.f,0.f,0.f,0.f}};

    // ---- build: 4-lane cluster per n; lane j computes o-quad j ----
    auto build_round = [&](int n) {
        const float4* wp = reinterpret_cast<const float4*>(
            w + ((size_t)c * NN + n) * (KI * NO));
        float xs[TB][KI];
        #pragma unroll
        for (int tb = 0; tb < TB; ++tb) {
            const float4* xp = reinterpret_cast<const float4*>(
                x + ((size_t)(b0 + tb) * NN + n) * KI);
            float4 a = xp[0], b = xp[1];   // same addr across cluster -> bcast
            xs[tb][0]=a.x; xs[tb][1]=a.y; xs[tb][2]=a.z; xs[tb][3]=a.w;
            xs[tb][4]=b.x; xs[tb][5]=b.y; xs[tb][6]=b.z; xs[tb][7]=b.w;
        }
        float acc[TB][4] = {{0.f,0.f,0.f,0.f},{0.f,0.f,0.f,0.f}};
        #pragma unroll
        for (int i = 0; i < KI; ++i) {
            float4 wq = wp[i * 4 + j];
            #pragma unroll
            for (int tb = 0; tb < TB; ++tb) {
                acc[tb][0] = fmaf(xs[tb][i], wq.x, acc[tb][0]);
                acc[tb][1] = fmaf(xs[tb][i], wq.y, acc[tb][1]);
                acc[tb][2] = fmaf(xs[tb][i], wq.z, acc[tb][2]);
                acc[tb][3] = fmaf(xs[tb][i], wq.w, acc[tb][3]);
            }
        }
        // lane j holds ops {4j..4j+3} = pairs {2j, 2j+1} = 8B in quad j>>1
        const int q = j >> 1, h = j & 1;
        #pragma unroll
        for (int tb = 0; tb < TB; ++tb) {
            bs[tb][0] += acc[tb][0]; bs[tb][1] += acc[tb][1];
            bs[tb][2] += acc[tb][2]; bs[tb][3] += acc[tb][3];
            unsigned p0, p1;   // pair: even op lo16, odd op hi16 (RNE)
            asm("v_cvt_pk_bf16_f32 %0, %1, %2"
                : "=v"(p0) : "v"(acc[tb][0]), "v"(acc[tb][1]));
            asm("v_cvt_pk_bf16_f32 %0, %1, %2"
                : "=v"(p1) : "v"(acc[tb][2]), "v"(acc[tb][3]));
            uint2 pk; pk.x = p0; pk.y = p1;
            *reinterpret_cast<uint2*>(
                &s_pr[tb * (NN * 8) + slotof(n, q) * 4 + h * 2]) = pk;
        }
    };
    #pragma unroll 1
    for (int r = 0; r < 4; ++r) build_round(r * 256 + g);
    if (g < 128) build_round(1024 + g);      // wave-uniform (t < 512)

    // reduce bs across the wave's 16 clusters (same j): lanes 0..3 write
    #pragma unroll
    for (int tb = 0; tb < TB; ++tb)
        #pragma unroll
        for (int k = 0; k < 4; ++k) {
            float s = bs[tb][k];
            s += __shfl_xor(s, 4);  s += __shfl_xor(s, 8);
            s += __shfl_xor(s, 16); s += __shfl_xor(s, 32);
            bs[tb][k] = s;
        }
    if (lane < 4) {
        #pragma unroll
        for (int tb = 0; tb < TB; ++tb) {
            s_red2[wv][tb][4*lane+0] = bs[tb][0];
            s_red2[wv][tb][4*lane+1] = bs[tb][1];
            s_red2[wv][tb][4*lane+2] = bs[tb][2];
            s_red2[wv][tb][4*lane+3] = bs[tb][3];
        }
    }
    __syncthreads();

    // ---- finalize: combine waves, softmax-normalize, squash ----
    auto finalize = [&](int iter) {
        if (t < TB * NO) {
            const int tb = t >> 4, oc = t & 15;
            float acc = 0.f, lt = 0.f;
            #pragma unroll
            for (int w2 = 0; w2 < NWV; ++w2) {
                acc += s_red2[w2][tb][oc];
                if (iter > 0) lt += s_ls[w2][tb];
            }
            if (iter == 0) lt = (float)NN;   // softmax(0) is uniform
            float s_o = acc / lt;
            float sq = s_o * s_o;
            sq += __shfl_xor(sq, 1); sq += __shfl_xor(sq, 2);
            sq += __shfl_xor(sq, 4); sq += __shfl_xor(sq, 8);
            float scale = sq / ((1.f + sq) * sqrtf(sq));
            float vo = s_o * scale;
            s_v[tb][oc] = vo;
            if (iter == NITER - 1)
                out[((size_t)c * NB + b0 + tb) * NO + oc] = vo;
        }
    };

    // consumption: thread owns n=t (and 1024+t if t<128) -> private logits;
    // delta + exp + weighted-sum fused in ONE pass over the bf16 priors.
    float logit[2][TB] = {{0.f,0.f},{0.f,0.f}};

    auto routing_pass = [&]() {
        #pragma unroll
        for (int tb = 0; tb < TB; ++tb) {
            float vv[NO];
            {
                const float4* vp = reinterpret_cast<const float4*>(&s_v[tb][0]);
                float4 a = vp[0], b = vp[1], cc = vp[2], d4 = vp[3];
                vv[0]=a.x;  vv[1]=a.y;  vv[2]=a.z;  vv[3]=a.w;
                vv[4]=b.x;  vv[5]=b.y;  vv[6]=b.z;  vv[7]=b.w;
                vv[8]=cc.x; vv[9]=cc.y; vv[10]=cc.z; vv[11]=cc.w;
                vv[12]=d4.x; vv[13]=d4.y; vv[14]=d4.z; vv[15]=d4.w;
            }
            float sp[NO];
            #pragma unroll
            for (int o = 0; o < NO; ++o) sp[o] = 0.f;
            float lse = 0.f;
            #pragma unroll
            for (int rr = 0; rr < 2; ++rr) {
                if (rr == 1 && t >= 128) continue;   // wave-uniform
                const int n = rr * 1024 + t;
                const unsigned* base = &s_pr[tb * (NN * 8)];
                uint4 qa = *reinterpret_cast<const uint4*>(&base[slotof(n, 0) * 4]);
                uint4 qb = *reinterpret_cast<const uint4*>(&base[slotof(n, 1) * 4]);
                unsigned u[8] = {qa.x, qa.y, qa.z, qa.w, qb.x, qb.y, qb.z, qb.w};
                float d = 0.f;
                #pragma unroll
                for (int op = 0; op < 8; ++op) {
                    float lo = __uint_as_float(u[op] << 16);
                    float hi = __uint_as_float(u[op] & 0xffff0000u);
                    d = fmaf(lo, vv[2*op+0], d);
                    d = fmaf(hi, vv[2*op+1], d);
                }
                logit[rr][tb] += d;        // |logit| <~ 30: fp32 exact-safe
                float e = __expf(logit[rr][tb]);
                lse += e;
                #pragma unroll
                for (int op = 0; op < 8; ++op) {
                    float lo = __uint_as_float(u[op] << 16);
                    float hi = __uint_as_float(u[op] & 0xffff0000u);
                    sp[2*op+0] = fmaf(e, lo, sp[2*op+0]);
                    sp[2*op+1] = fmaf(e, hi, sp[2*op+1]);
                }
            }
            // exp-sum: full-wave butterfly
            float s = lse;
            s += __shfl_xor(s, 1);  s += __shfl_xor(s, 2);
            s += __shfl_xor(s, 4);  s += __shfl_xor(s, 8);
            s += __shfl_xor(s, 16); s += __shfl_xor(s, 32);
            if (lane == 0) s_ls[wv][tb] = s;
            // comp-halving fold: 16 comps over 16-lane groups in 15 shuffles
            float g8[8];
            #pragma unroll
            for (int r = 0; r < 8; ++r) {
                float keep = bl0 ? sp[2*r+1] : sp[2*r];
                float send = bl0 ? sp[2*r]   : sp[2*r+1];
                g8[r] = keep + __shfl_xor(send, 1);
            }
            float g4[4];
            #pragma unroll
            for (int r = 0; r < 4; ++r) {
                float keep = bl1 ? g8[2*r+1] : g8[2*r];
                float send = bl1 ? g8[2*r]   : g8[2*r+1];
                g4[r] = keep + __shfl_xor(send, 2);
            }
            float g2[2];
            #pragma unroll
            for (int r = 0; r < 2; ++r) {
                float keep = bl2 ? g4[2*r+1] : g4[2*r];
                float send = bl2 ? g4[2*r]   : g4[2*r+1];
                g2[r] = keep + __shfl_xor(send, 4);
            }
            float g1;
            {
                float keep = bl3 ? g2[1] : g2[0];
                float send = bl3 ? g2[0] : g2[1];
                g1 = keep + __shfl_xor(send, 8);
            }
            g1 += __shfl_xor(g1, 16);
            g1 += __shfl_xor(g1, 32);
            if (lane < NO) s_red2[wv][tb][lane] = g1;
        }
    };

    finalize(0);          // v1 from uniform probs (build-side f32 sums)
    __syncthreads();
    routing_pass();       // logits += prior.v1; sums for iter 2
    __syncthreads();
    finalize(1);          // v2
    __syncthreads();
    routing_pass();       // logits += prior.v2; sums for iter 3
    __syncthreads();
    finalize(2);          // v3 -> out
}

extern "C" void kernel_launch(void* const* d_in, const int* in_sizes, int n_in,
                              void* d_out, int out_size, void* d_ws, size_t ws_size,
                              hipStream_t stream) {
    const float* x = (const float*)d_in[0];
    const float* w = (const float*)d_in[1];
    float* out = (float*)d_out;
    capsule_kernel<<<dim3(NCAP * (NB / TB)), dim3(NT), 0, stream>>>(x, w, out);
}